// Round 2
// baseline (125.084 us; speedup 1.0000x reference)
//
#include <hip/hip_runtime.h>
#include <hip/hip_bf16.h>
#include <hip/hip_fp16.h>
#include <stdint.h>

typedef __attribute__((ext_vector_type(8))) _Float16 f16x8;
typedef __attribute__((ext_vector_type(4))) float f32x4;
typedef __attribute__((ext_vector_type(4))) int i32x4;

#define GLD_LDS16(g, l) __builtin_amdgcn_global_load_lds( \
    (const __attribute__((address_space(1))) uint32_t*)(g), \
    (__attribute__((address_space(3))) uint32_t*)(l), 16, 0, 0)

// ---------------- W fp32 -> fp16 (into workspace), 512x2048 -------------
__global__ __launch_bounds__(256) void k_cvt_w(const float* __restrict__ W,
                                               _Float16* __restrict__ Wh) {
  int i = (blockIdx.x * 256 + threadIdx.x) * 8;  // 1048576 elems total
  float4 a = *(const float4*)(W + i);
  float4 b = *(const float4*)(W + i + 4);
  union { _Float16 h[8]; i32x4 v; } u;
  u.h[0] = (_Float16)a.x; u.h[1] = (_Float16)a.y;
  u.h[2] = (_Float16)a.z; u.h[3] = (_Float16)a.w;
  u.h[4] = (_Float16)b.x; u.h[5] = (_Float16)b.y;
  u.h[6] = (_Float16)b.z; u.h[7] = (_Float16)b.w;
  *(i32x4*)(Wh + i) = u.v;
}

__device__ inline float softplus_f(float x) {
  float e = __expf(-fabsf(x));
  return fmaxf(x, 0.f) + __logf(1.f + e);
}

// ---- fused GEMM(fp16x2-split MFMA) + softplus-diff + sigmoid ----
// Block: 64 rows x 512 hid cols, K=2048 in 32 steps of 64.
// 8 waves in 2Mx4N grid: each wave 32 rows x 128 cols.
// A: global->regs directly in fragment layout (no LDS). B: gld_lds double-buffer.
// Single barrier per K-step; all prefetch issued before the MFMA cluster.
__global__ __launch_bounds__(512, 2) void k_main(
    const float* __restrict__ X,      // [16384][2048]
    const _Float16* __restrict__ Wh,  // [512][2048]
    const float* __restrict__ U,      // [512][2]
    const float* __restrict__ hb,     // [512]
    const float* __restrict__ yb,     // [2]
    float* __restrict__ out) {        // [16384][2]
  __shared__ __align__(16) _Float16 Bs[2][512 * 64];  // 128 KB
  __shared__ float sD[64];

  const int t = threadIdx.x;
  const int lane = t & 63;
  const int wid = t >> 6;  // 0..7
  const int wm = wid >> 2; // 0..1  (M half)
  const int wn = wid & 3;  // 0..3  (N quarter)
  const int bm0 = blockIdx.x * 64;
  const int lrow = lane & 15, lq = lane >> 4;

  if (t < 64) sD[t] = 0.f;

  f32x4 acc[2][8];  // [mf][nf]
#pragma unroll
  for (int m = 0; m < 2; ++m)
#pragma unroll
    for (int n = 0; n < 8; ++n) acc[m][n] = (f32x4){0.f, 0.f, 0.f, 0.f};

  // B staging: wave wid stages W cols [wid*64, wid*64+64). Pre-swizzled
  // global source (m173): phys 16B slot s holds logical chunk s^(row&7).
  const int r8 = lane >> 3, s8 = lane & 7;
  const _Float16* wptr = Wh + (size_t)(wid * 64 + r8) * 2048 + ((s8 ^ r8) << 3);

  // A direct-load base: lane -> row (l&15), k-chunk (l>>4)*8 floats.
  const float* xbase = X + (size_t)(bm0 + wm * 32 + lrow) * 2048 + lq * 8;

  f32x4 araw[2][2][2];  // [ks][mf][half] — all indices compile-time
  // ---- prologue: A(0) + B(0) ----
#pragma unroll
  for (int ks = 0; ks < 2; ++ks)
#pragma unroll
    for (int mf = 0; mf < 2; ++mf) {
      const float* p = xbase + mf * 16 * 2048 + ks * 32;
      araw[ks][mf][0] = *(const f32x4*)p;
      araw[ks][mf][1] = *(const f32x4*)(p + 4);
    }
  {
    char* bw = (char*)&Bs[0][0] + wid * 64 * 128;
#pragma unroll
    for (int i = 0; i < 8; ++i)
      GLD_LDS16(wptr + (size_t)i * 8 * 2048, bw + i * 1024);
  }
  __syncthreads();

  for (int kt = 0; kt < 32; ++kt) {
    const int cb = kt & 1;
    const int k0n = (kt < 31 ? (kt + 1) : 31) * 64;  // clamped prefetch

    // convert A(kt) raw fp32 -> hi/lo fp16 fragments (in-register split)
    f16x8 ah[2][2], al[2][2];  // [ks][mf]
#pragma unroll
    for (int ks = 0; ks < 2; ++ks)
#pragma unroll
      for (int mf = 0; mf < 2; ++mf)
#pragma unroll
        for (int h = 0; h < 2; ++h)
#pragma unroll
          for (int j = 0; j < 4; ++j) {
            float v = araw[ks][mf][h][j];
            _Float16 hi = (_Float16)v;
            ah[ks][mf][h * 4 + j] = hi;
            al[ks][mf][h * 4 + j] = (_Float16)(v - (float)hi);
          }

    // issue A(kt+1) global loads (HBM latency hides under MFMA below)
#pragma unroll
    for (int ks = 0; ks < 2; ++ks)
#pragma unroll
      for (int mf = 0; mf < 2; ++mf) {
        const float* p = xbase + mf * 16 * 2048 + k0n + ks * 32;
        araw[ks][mf][0] = *(const f32x4*)p;
        araw[ks][mf][1] = *(const f32x4*)(p + 4);
      }
    // issue B(kt+1) staging into the other buffer
    {
      char* bw = (char*)&Bs[cb ^ 1][0] + wid * 64 * 128;
#pragma unroll
      for (int i = 0; i < 8; ++i)
        GLD_LDS16(wptr + (size_t)i * 8 * 2048 + k0n, bw + i * 1024);
    }

    // compute on B(kt)
    const char* bbase = (const char*)&Bs[cb][0];
#pragma unroll
    for (int ks = 0; ks < 2; ++ks) {
      f16x8 bf[8];
#pragma unroll
      for (int nf = 0; nf < 8; ++nf) {
        int row = wn * 128 + nf * 16 + lrow;
        int off = row * 128 + ((ks * 64 + lq * 16) ^ ((row & 7) << 4));
        bf[nf] = *(const f16x8*)(bbase + off);
      }
      __builtin_amdgcn_s_setprio(1);
#pragma unroll
      for (int mf = 0; mf < 2; ++mf)
#pragma unroll
        for (int nf = 0; nf < 8; ++nf) {
          acc[mf][nf] = __builtin_amdgcn_mfma_f32_16x16x32_f16(
              ah[ks][mf], bf[nf], acc[mf][nf], 0, 0, 0);
          acc[mf][nf] = __builtin_amdgcn_mfma_f32_16x16x32_f16(
              al[ks][mf], bf[nf], acc[mf][nf], 0, 0, 0);
        }
      __builtin_amdgcn_s_setprio(0);
    }
    __syncthreads();  // drains vmcnt(0): B(kt+1) landed, A(kt+1) in regs
  }

  // ---- epilogue: softplus-difference, per-row reduce, sigmoid ----
  // acc[mf][nf][r]: row = bm0 + wm*32 + mf*16 + lq*4 + r
  //                 col = wn*128 + nf*16 + lrow
  float dpart[8];
#pragma unroll
  for (int i = 0; i < 8; ++i) dpart[i] = 0.f;
#pragma unroll
  for (int nf = 0; nf < 8; ++nf) {
    int h = wn * 128 + nf * 16 + lrow;
    float hbv = hb[h];
    float u0 = U[2 * h], u1 = U[2 * h + 1];
#pragma unroll
    for (int mf = 0; mf < 2; ++mf)
#pragma unroll
      for (int r = 0; r < 4; ++r) {
        float pf = acc[mf][nf][r] + hbv;
        dpart[mf * 4 + r] += softplus_f(pf + u0) - softplus_f(pf + u1);
      }
  }
#pragma unroll
  for (int i = 0; i < 8; ++i) {
    float v = dpart[i];
    v += __shfl_xor(v, 1);
    v += __shfl_xor(v, 2);
    v += __shfl_xor(v, 4);
    v += __shfl_xor(v, 8);
    dpart[i] = v;
  }
  if (lrow == 0) {
#pragma unroll
    for (int mf = 0; mf < 2; ++mf)
#pragma unroll
      for (int r = 0; r < 4; ++r)
        atomicAdd(&sD[wm * 32 + mf * 16 + lq * 4 + r], dpart[mf * 4 + r]);
  }
  __syncthreads();
  if (t < 64) {
    float Dl = sD[t] + yb[0] - yb[1];  // logit0 - logit1
    float o0 = 1.f / (1.f + __expf(-Dl));
    float o1 = 1.f / (1.f + __expf(Dl));
    *(float2*)(out + (size_t)(bm0 + t) * 2) = make_float2(o0, o1);
  }
}

extern "C" void kernel_launch(void* const* d_in, const int* in_sizes, int n_in,
                              void* d_out, int out_size, void* d_ws,
                              size_t ws_size, hipStream_t stream) {
  const float* X = (const float*)d_in[0];
  const float* W = (const float*)d_in[1];
  const float* U = (const float*)d_in[2];
  const float* hb = (const float*)d_in[3];
  const float* yb = (const float*)d_in[4];
  float* out = (float*)d_out;
  _Float16* Wh = (_Float16*)d_ws;  // 512*2048*2 = 2 MB scratch

  hipLaunchKernelGGL(k_cvt_w, dim3(512), dim3(256), 0, stream, W, Wh);
  hipLaunchKernelGGL(k_main, dim3(256), dim3(512), 0, stream, X, Wh, U, hb, yb,
                     out);
}

// Round 4
// 92.449 us; speedup vs baseline: 1.3530x; 1.3530x over previous
//
#include <hip/hip_runtime.h>
#include <hip/hip_bf16.h>
#include <hip/hip_fp16.h>
#include <stdint.h>

typedef __attribute__((ext_vector_type(8))) _Float16 f16x8;
typedef __attribute__((ext_vector_type(4))) _Float16 f16x4;
typedef __attribute__((ext_vector_type(4))) float f32x4;
typedef __attribute__((ext_vector_type(4))) int i32x4;

#define GLD_LDS16(g, l) __builtin_amdgcn_global_load_lds( \
    (const __attribute__((address_space(1))) uint32_t*)(g), \
    (__attribute__((address_space(3))) uint32_t*)(l), 16, 0, 0)

// ---------------- W fp32 -> fp16 (into workspace), 512x2048 -------------
__global__ __launch_bounds__(256) void k_cvt_w(const float* __restrict__ W,
                                               _Float16* __restrict__ Wh) {
  int i = (blockIdx.x * 256 + threadIdx.x) * 8;  // 1048576 elems total
  float4 a = *(const float4*)(W + i);
  float4 b = *(const float4*)(W + i + 4);
  union { _Float16 h[8]; i32x4 v; } u;
  u.h[0] = (_Float16)a.x; u.h[1] = (_Float16)a.y;
  u.h[2] = (_Float16)a.z; u.h[3] = (_Float16)a.w;
  u.h[4] = (_Float16)b.x; u.h[5] = (_Float16)b.y;
  u.h[6] = (_Float16)b.z; u.h[7] = (_Float16)b.w;
  *(i32x4*)(Wh + i) = u.v;
}

__device__ inline float softplus_f(float x) {
  float e = __expf(-fabsf(x));
  return fmaxf(x, 0.f) + __logf(1.f + e);
}

// ---- fused GEMM(fp16x2-split MFMA) + softplus-diff partial ----
// Block: 64 rows x 256 hid cols (N-split by 2), BK=32, 64 K-steps.
// grid 512 -> 2 blocks/CU (LDS 48KB) for cross-block latency hiding (m114).
// 8 waves 2Mx4N: wave = 32 rows x 64 cols. A: staged to LDS as fp16 hi/lo
// (cvt ONCE per element). B: gld_lds w/ pre-swizzled source. One barrier/iter.
__global__ __launch_bounds__(512, 4) void k_main(
    const float* __restrict__ X,      // [16384][2048]
    const _Float16* __restrict__ Wh,  // [512][2048]
    const float* __restrict__ U,      // [512][2]
    const float* __restrict__ hb,     // [512]
    float* __restrict__ Dp) {         // [2][16384] partial logit-diffs
  __shared__ __align__(16) _Float16 AhS[2][64 * 32];   // 2 x 4 KB
  __shared__ __align__(16) _Float16 AlS[2][64 * 32];   // 2 x 4 KB
  __shared__ __align__(16) _Float16 BsS[2][256 * 32];  // 2 x 16 KB
  __shared__ float sD[64];

  const int t = threadIdx.x;
  const int lane = t & 63;
  const int wid = t >> 6;   // 0..7
  const int wm = wid >> 2;  // 0..1 (M half)
  const int wn = wid & 3;   // 0..3 (N quarter)
  const int bx = blockIdx.x;
  const int bm0 = (bx >> 1) * 64;
  const int nhalf = bx & 1;
  const int bn0 = nhalf * 256;
  const int lrow = lane & 15, lq = lane >> 4;

  if (t < 64) sD[t] = 0.f;

  f32x4 acc[2][4];
#pragma unroll
  for (int m = 0; m < 2; ++m)
#pragma unroll
    for (int n = 0; n < 4; ++n) acc[m][n] = (f32x4){0.f, 0.f, 0.f, 0.f};

  // A staging: thread t -> row t>>3, float4 chunk t&7. Swizzled ds_write:
  // phys byte = (row*64 + slot*16) ^ ((row&7)<<4), slot=(t&7)>>1, half=t&1.
  const int ar = t >> 3, ac = t & 7;
  const float* xsrc = X + (size_t)(bm0 + ar) * 2048 + ac * 4;
  const int awoff = (((ar * 64) + ((ac >> 1) << 4)) ^ ((ar & 7) << 4)) + (ac & 1) * 8;

  // B staging: wave wid covers B rows [wid*32, wid*32+32): 2 gld_lds of 1KB.
  // Linear LDS dest; source pre-permuted so phys slot p holds logical
  // i = p ^ (p>>2) ^ (p>>4) within each 512B (8-row) group (inverse of the
  // read-side XOR ((row&7)<<4)).
  const int pp = lane & 31;
  const int ii = pp ^ (pp >> 2) ^ (pp >> 4);
  const int brow = wid * 32 + (lane >> 5) * 8 + (ii >> 2);
  const _Float16* bsrc = Wh + (size_t)(bn0 + brow) * 2048 + (ii & 3) * 8;

#define CVT_STORE_A(ARC, NXT) do {                                        \
    f16x4 hv, lv;                                                          \
    _Pragma("unroll") for (int j = 0; j < 4; ++j) {                        \
      _Float16 hj = (_Float16)(ARC)[j];                                    \
      hv[j] = hj; lv[j] = (_Float16)((ARC)[j] - (float)hj);                \
    }                                                                      \
    *(f16x4*)((char*)&AhS[NXT][0] + awoff) = hv;                           \
    *(f16x4*)((char*)&AlS[NXT][0] + awoff) = lv;                           \
  } while (0)

#define SUBITER(CUR, NXT, ARC, ARL, KT) do {                               \
    const int ktn = ((KT) < 63) ? (KT) + 1 : 63;                           \
    const int ktn2 = ((KT) < 62) ? (KT) + 2 : 63;                          \
    GLD_LDS16(bsrc + (size_t)ktn * 32,                                     \
              (char*)&BsS[NXT][0] + wid * 2048);                           \
    GLD_LDS16(bsrc + (size_t)ktn * 32 + 16 * 2048,                         \
              (char*)&BsS[NXT][0] + wid * 2048 + 1024);                    \
    CVT_STORE_A(ARC, NXT);        /* A(KT+1) -> LDS[NXT] */                \
    ARL = *(const f32x4*)(xsrc + (size_t)ktn2 * 32); /* A(KT+2) -> regs */ \
    {                                                                      \
      f16x8 fah[2], fal[2], fbf[4];                                        \
      _Pragma("unroll") for (int mf = 0; mf < 2; ++mf) {                   \
        int row = wm * 32 + mf * 16 + lrow;                                \
        int off = (row * 64 + lq * 16) ^ ((row & 7) << 4);                 \
        fah[mf] = *(const f16x8*)((const char*)&AhS[CUR][0] + off);        \
        fal[mf] = *(const f16x8*)((const char*)&AlS[CUR][0] + off);        \
      }                                                                    \
      _Pragma("unroll") for (int nf = 0; nf < 4; ++nf) {                   \
        int row = wn * 64 + nf * 16 + lrow;                                \
        int off = (row * 64 + lq * 16) ^ ((row & 7) << 4);                 \
        fbf[nf] = *(const f16x8*)((const char*)&BsS[CUR][0] + off);        \
      }                                                                    \
      __builtin_amdgcn_s_setprio(1);                                       \
      _Pragma("unroll") for (int mf = 0; mf < 2; ++mf)                     \
        _Pragma("unroll") for (int nf = 0; nf < 4; ++nf) {                 \
          acc[mf][nf] = __builtin_amdgcn_mfma_f32_16x16x32_f16(            \
              fah[mf], fbf[nf], acc[mf][nf], 0, 0, 0);                     \
          acc[mf][nf] = __builtin_amdgcn_mfma_f32_16x16x32_f16(            \
              fal[mf], fbf[nf], acc[mf][nf], 0, 0, 0);                     \
        }                                                                  \
      __builtin_amdgcn_s_setprio(0);                                       \
    }                                                                      \
    __syncthreads();                                                       \
  } while (0)

  // ---- prologue: tile 0 to LDS[0], tile 1 to regs ----
  f32x4 arA = *(const f32x4*)(xsrc);
  GLD_LDS16(bsrc, (char*)&BsS[0][0] + wid * 2048);
  GLD_LDS16(bsrc + 16 * 2048, (char*)&BsS[0][0] + wid * 2048 + 1024);
  CVT_STORE_A(arA, 0);
  f32x4 arB = *(const f32x4*)(xsrc + 32);
  __syncthreads();

  for (int kt2 = 0; kt2 < 32; ++kt2) {
    SUBITER(0, 1, arB, arA, 2 * kt2);
    SUBITER(1, 0, arA, arB, 2 * kt2 + 1);
  }

  // ---- epilogue: softplus-difference partial for this N-half ----
  // acc[mf][nf][r]: row = bm0 + wm*32 + mf*16 + lq*4 + r
  //                 col = bn0 + wn*64 + nf*16 + lrow
  float dpart[8];
#pragma unroll
  for (int i = 0; i < 8; ++i) dpart[i] = 0.f;
#pragma unroll
  for (int nf = 0; nf < 4; ++nf) {
    int h = bn0 + wn * 64 + nf * 16 + lrow;
    float hbv = hb[h];
    float u0 = U[2 * h], u1 = U[2 * h + 1];
#pragma unroll
    for (int mf = 0; mf < 2; ++mf)
#pragma unroll
      for (int r = 0; r < 4; ++r) {
        float pf = acc[mf][nf][r] + hbv;
        dpart[mf * 4 + r] += softplus_f(pf + u0) - softplus_f(pf + u1);
      }
  }
#pragma unroll
  for (int i = 0; i < 8; ++i) {
    float v = dpart[i];
    v += __shfl_xor(v, 1);
    v += __shfl_xor(v, 2);
    v += __shfl_xor(v, 4);
    v += __shfl_xor(v, 8);
    dpart[i] = v;
  }
  if (lrow == 0) {
#pragma unroll
    for (int mf = 0; mf < 2; ++mf)
#pragma unroll
      for (int r = 0; r < 4; ++r)
        atomicAdd(&sD[wm * 32 + mf * 16 + lq * 4 + r], dpart[mf * 4 + r]);
  }
  __syncthreads();
  if (t < 64) Dp[nhalf * 16384 + bm0 + t] = sD[t];
}

// ---- combine the two N-half partials + sigmoid ----
__global__ __launch_bounds__(256) void k_final(const float* __restrict__ Dp,
                                               const float* __restrict__ yb,
                                               float* __restrict__ out) {
  int i = blockIdx.x * 256 + threadIdx.x;  // 0..16383
  float D = Dp[i] + Dp[16384 + i] + yb[0] - yb[1];  // logit0 - logit1
  float e = __expf(-D);
  float o0 = 1.f / (1.f + e);
  float o1 = e * o0;
  *(float2*)(out + (size_t)i * 2) = make_float2(o0, o1);
}

extern "C" void kernel_launch(void* const* d_in, const int* in_sizes, int n_in,
                              void* d_out, int out_size, void* d_ws,
                              size_t ws_size, hipStream_t stream) {
  const float* X = (const float*)d_in[0];
  const float* W = (const float*)d_in[1];
  const float* U = (const float*)d_in[2];
  const float* hb = (const float*)d_in[3];
  const float* yb = (const float*)d_in[4];
  float* out = (float*)d_out;
  _Float16* Wh = (_Float16*)d_ws;                          // 2 MB
  float* Dp = (float*)((char*)d_ws + 2 * 1024 * 1024);     // 128 KB partials

  hipLaunchKernelGGL(k_cvt_w, dim3(512), dim3(256), 0, stream, W, Wh);
  hipLaunchKernelGGL(k_main, dim3(512), dim3(512), 0, stream, X, Wh, U, hb, Dp);
  hipLaunchKernelGGL(k_final, dim3(64), dim3(256), 0, stream, Dp, yb, out);
}